// Round 1
// baseline (4810.805 us; speedup 1.0000x reference)
//
#include <hip/hip_runtime.h>

// Fast-mode NLM, PATCH=5 (o=2), DIST=6 (D=6) -> 169 shifts, h=0.05.
// w = exp(-boxsum * 16)  [boxsum = 25 * box_mean of sq diff; 400/25 = 16]
//
// Layout: one block = 64x128 output tile of one (b,c) plane.
// Stage (128+16)x(64+16) reflect-padded fp32 tile in LDS (stride 85 to
// de-conflict the 8-row strip offset: 8*85=680 ≡ 8 mod 32 banks).
// Thread = 4 cols x 8-row strip; vertical sliding 5-row box via register
// ring buffer (fully unrolled -> static indexing), horizontal sliding sum
// over an 8-wide sq-diff span.

#define HH 768
#define WW 768
#define NPL 32            // B*C = 8*4
#define TW 64
#define TH 128
#define HALO 8            // D + o
#define DD 6
#define LR (TH + 2*HALO)  // 144
#define LC (TW + 2*HALO)  // 80
#define LS 85             // LDS row stride (floats); 8*85 % 32 == 8 -> no ty bank clash
#define STRIP 8

__global__ __launch_bounds__(256, 3)
void nlm_kernel(const float* __restrict__ in, float* __restrict__ out) {
    __shared__ float L[LR * LS];

    const int plane = blockIdx.z;
    const int ty0 = blockIdx.y * TH;
    const int tx0 = blockIdx.x * TW;
    const float* __restrict__ src = in + (size_t)plane * (HH * WW);

    // ---- stage tile + halo into LDS (reflect pad, clip to [0,1]) ----
    const int tid = threadIdx.y * 16 + threadIdx.x;
    for (int idx = tid; idx < LR * LC; idx += 256) {
        int r = idx / LC;
        int c = idx - r * LC;
        int gy = ty0 - HALO + r;
        int gx = tx0 - HALO + c;
        gy = (gy < 0) ? -gy : ((gy >= HH) ? 2 * HH - 2 - gy : gy);
        gx = (gx < 0) ? -gx : ((gx >= WW) ? 2 * WW - 2 - gx : gx);
        float v = src[gy * WW + gx];
        L[r * LS + c] = fminf(fmaxf(v, 0.0f), 1.0f);
    }
    __syncthreads();

    const int tx  = threadIdx.x;       // 0..15 -> 4 cols each
    const int tyi = threadIdx.y;       // 0..15 -> 8-row strip each
    const int cx  = HALO + tx * 4;     // LDS col of first owned output col
    const int oy0 = tyi * STRIP;       // first owned output row (tile-local)

    float num[STRIP][4];
    float den[STRIP][4];
#pragma unroll
    for (int r = 0; r < STRIP; ++r)
#pragma unroll
        for (int c = 0; c < 4; ++c) { num[r][c] = 0.0f; den[r][c] = 0.0f; }

    const float* baseu = L + (cx - 2);   // + rr*LS gives row window base

    for (int dy = -DD; dy <= DD; ++dy) {
        for (int dx = -DD; dx <= DD; ++dx) {
            const int so = dy * LS + dx;      // shifted-vs-unshifted LDS offset

            // ---- prime: 5-row box window for output row oy0 ----
            float rs[5][4];                   // ring of row-sums (static idx)
            float dsum[4] = {0.f, 0.f, 0.f, 0.f};
#pragma unroll
            for (int i = 0; i < 5; ++i) {
                const float* u = baseu + (oy0 + 6 + i) * LS;
                const float* s = u + so;
                float sq[8];
#pragma unroll
                for (int k = 0; k < 8; ++k) { float t = u[k] - s[k]; sq[k] = t * t; }
                float r0 = ((sq[0] + sq[1]) + (sq[2] + sq[3])) + sq[4];
                float r1 = r0 - sq[0] + sq[5];
                float r2 = r1 - sq[1] + sq[6];
                float r3 = r2 - sq[2] + sq[7];
                rs[i][0] = r0; rs[i][1] = r1; rs[i][2] = r2; rs[i][3] = r3;
                dsum[0] += r0; dsum[1] += r1; dsum[2] += r2; dsum[3] += r3;
            }

            // ---- slide down the strip ----
#pragma unroll
            for (int step = 0; step < STRIP; ++step) {
                const float* vp = L + (HALO + oy0 + step + dy) * LS + cx + dx;
#pragma unroll
                for (int c = 0; c < 4; ++c) {
                    float w = __expf(dsum[c] * -16.0f);
                    num[step][c] += w * vp[c];
                    den[step][c] += w;
                }
                if (step < STRIP - 1) {
                    const float* u = baseu + (oy0 + step + 11) * LS;
                    const float* s = u + so;
                    float sq[8];
#pragma unroll
                    for (int k = 0; k < 8; ++k) { float t = u[k] - s[k]; sq[k] = t * t; }
                    float r0 = ((sq[0] + sq[1]) + (sq[2] + sq[3])) + sq[4];
                    float r1 = r0 - sq[0] + sq[5];
                    float r2 = r1 - sq[1] + sq[6];
                    float r3 = r2 - sq[2] + sq[7];
                    const int slot = step % 5;   // static under full unroll
                    dsum[0] += r0 - rs[slot][0]; rs[slot][0] = r0;
                    dsum[1] += r1 - rs[slot][1]; rs[slot][1] = r1;
                    dsum[2] += r2 - rs[slot][2]; rs[slot][2] = r2;
                    dsum[3] += r3 - rs[slot][3]; rs[slot][3] = r3;
                }
            }
        }
    }

    // ---- epilogue: out = num/den, float4 stores ----
    float* __restrict__ dst = out + (size_t)plane * (HH * WW)
                            + (size_t)(ty0 + oy0) * WW + (tx0 + tx * 4);
#pragma unroll
    for (int r = 0; r < STRIP; ++r) {
        float4 o;
        o.x = num[r][0] / den[r][0];
        o.y = num[r][1] / den[r][1];
        o.z = num[r][2] / den[r][2];
        o.w = num[r][3] / den[r][3];
        *reinterpret_cast<float4*>(dst + (size_t)r * WW) = o;
    }
}

extern "C" void kernel_launch(void* const* d_in, const int* in_sizes, int n_in,
                              void* d_out, int out_size, void* d_ws, size_t ws_size,
                              hipStream_t stream) {
    const float* x = (const float*)d_in[0];
    float* out = (float*)d_out;
    dim3 grid(WW / TW, HH / TH, NPL);   // 12 x 6 x 32 = 2304 blocks
    dim3 block(16, 16);
    nlm_kernel<<<grid, block, 0, stream>>>(x, out);
}